// Round 1
// baseline (502.102 us; speedup 1.0000x reference)
//
#include <hip/hip_runtime.h>
#include <math.h>

// Problem constants
#define BB 2
#define TT 2048
#define CC 2048
#define HH 16
#define HKK 4
#define HD 128
#define MM (BB*TT)          // 4096 rows

typedef short bf16x8 __attribute__((ext_vector_type(8)));
typedef float f32x4 __attribute__((ext_vector_type(4)));

#define GLOBAL_AS(p) ((const __attribute__((address_space(1))) void*)(p))
#define LDS_AS(p)    ((__attribute__((address_space(3))) void*)(p))

__device__ __forceinline__ unsigned short f2bf(float f) {
    unsigned u = __float_as_uint(f);
    u += 0x7fff + ((u >> 16) & 1);          // round-to-nearest-even
    return (unsigned short)(u >> 16);
}
__device__ __forceinline__ float bf2f(unsigned short h) {
    return __uint_as_float(((unsigned)h) << 16);
}

// softmax scale 1/sqrt(128) * log2(e), folded into q at projection time
#define QSCALE (0.08838834764831845f * 1.44269504088896340736f)

// ---------------------------------------------------------------------------
// cast x (f32 -> bf16), 8 elements/thread
// ---------------------------------------------------------------------------
__global__ __launch_bounds__(256) void cast_x_kernel(
    const float* __restrict__ x, unsigned short* __restrict__ xb)
{
    size_t i = ((size_t)blockIdx.x * 256 + threadIdx.x) * 8;
    float4 a = *(const float4*)&x[i];
    float4 b = *(const float4*)&x[i + 4];
    uint4 r;
    r.x = f2bf(a.x) | ((unsigned)f2bf(a.y) << 16);
    r.y = f2bf(a.z) | ((unsigned)f2bf(a.w) << 16);
    r.z = f2bf(b.x) | ((unsigned)f2bf(b.y) << 16);
    r.w = f2bf(b.z) | ((unsigned)f2bf(b.w) << 16);
    *(uint4*)&xb[i] = r;
}

// ---------------------------------------------------------------------------
// Weight transpose+cast: W[K][N] f32 -> Wt[N][K] bf16.
// ---------------------------------------------------------------------------
__global__ __launch_bounds__(256) void wtrans_kernel(
    const float* __restrict__ Wq, const float* __restrict__ Wk,
    const float* __restrict__ Wv, const float* __restrict__ Wo,
    unsigned short* __restrict__ Wt, unsigned short* __restrict__ Wot)
{
    __shared__ float tile[64][65];
    int z = blockIdx.z;
    const float* src; unsigned short* dst; int ldW, nmax, noff;
    if (z == 0)      { src = Wq; dst = Wt;  ldW = 2048; nmax = 2048; noff = 0; }
    else if (z == 1) { src = Wk; dst = Wt;  ldW = 512;  nmax = 512;  noff = 2048; }
    else if (z == 2) { src = Wv; dst = Wt;  ldW = 512;  nmax = 512;  noff = 2560; }
    else             { src = Wo; dst = Wot; ldW = 2048; nmax = 2048; noff = 0; }
    int n0 = blockIdx.y * 64;
    if (n0 >= nmax) return;
    int k0 = blockIdx.x * 64;
    int tx = threadIdx.x & 15, ty = threadIdx.x >> 4;
#pragma unroll
    for (int i = 0; i < 4; ++i) {
        int r = ty + i * 16;
        float4 v4 = *(const float4*)&src[(size_t)(k0 + r) * ldW + n0 + tx * 4];
        tile[r][tx * 4 + 0] = v4.x;
        tile[r][tx * 4 + 1] = v4.y;
        tile[r][tx * 4 + 2] = v4.z;
        tile[r][tx * 4 + 3] = v4.w;
    }
    __syncthreads();
#pragma unroll
    for (int i = 0; i < 4; ++i) {
        int r = ty + i * 16;     // n-local
        int c = tx * 4;          // k-local
        ushort4 o;
        o.x = f2bf(tile[c + 0][r]);
        o.y = f2bf(tile[c + 1][r]);
        o.z = f2bf(tile[c + 2][r]);
        o.w = f2bf(tile[c + 3][r]);
        *(ushort4*)&dst[(size_t)(noff + n0 + r) * 2048 + k0 + c] = o;
    }
}

// ---------------------------------------------------------------------------
// MFMA GEMM core 128x128x64, 4 waves, 16x16x32 bf16, global_load_lds staging,
// XOR-swizzled k-chunks.  mrow/nrow give each wave's 4 m/n tile bases.
// ---------------------------------------------------------------------------
__device__ __forceinline__ void gemm_core_128x128x64(
    const unsigned short* __restrict__ A, const unsigned short* __restrict__ B,
    short* As, short* Bs, int m0, int n0,
    const int* mrow, const int* nrow, f32x4 (&acc)[4][4])
{
    const int tid = threadIdx.x;
    const int lane = tid & 63;
    const int w = tid >> 6;
    const int lm = lane & 15;
    const int q8 = lane >> 4;
    const int lrow = lane >> 3;            // 0..7 within an instr's 8 rows
    const int lchunk = lane & 7;           // lane's LDS chunk slot

    for (int kt = 0; kt < CC; kt += 64) {
        __syncthreads();                   // prev iter frag reads complete
#pragma unroll
        for (int jj = 0; jj < 4; ++jj) {
            int rA = w * 32 + jj * 8 + lrow;
            int cA = ((lchunk ^ (rA & 7)) << 3);
            __builtin_amdgcn_global_load_lds(
                GLOBAL_AS(&A[(size_t)(m0 + rA) * CC + kt + cA]),
                LDS_AS(&As[(w * 32 + jj * 8) * 64]), 16, 0, 0);
            __builtin_amdgcn_global_load_lds(
                GLOBAL_AS(&B[(size_t)(n0 + rA) * CC + kt + cA]),
                LDS_AS(&Bs[(w * 32 + jj * 8) * 64]), 16, 0, 0);
        }
        __syncthreads();                   // vmcnt drained -> tiles visible
#pragma unroll
        for (int ksi = 0; ksi < 2; ++ksi) {
            bf16x8 af[4], bfr[4];
#pragma unroll
            for (int i = 0; i < 4; ++i) {
                int xo = (((ksi * 4 + q8) ^ (lm & 7)) << 3);
                af[i]  = *(const bf16x8*)&As[(mrow[i] + lm) * 64 + xo];
                bfr[i] = *(const bf16x8*)&Bs[(nrow[i] + lm) * 64 + xo];
            }
#pragma unroll
            for (int im = 0; im < 4; ++im)
#pragma unroll
                for (int in = 0; in < 4; ++in)
                    acc[im][in] = __builtin_amdgcn_mfma_f32_16x16x32_bf16(af[im], bfr[in], acc[im][in], 0, 0, 0);
        }
    }
}

// ---------------------------------------------------------------------------
// QKV GEMM with fused bias + RoPE + q-scale.  Each 128-col block is exactly
// one head (HD=128).  Wave n-tiles remapped to {w1*32+(in&1)*16+(in>>1)*64}
// so d and d^64 are in the SAME lane at in^2 -> in-register RoPE.
// ---------------------------------------------------------------------------
__global__ __launch_bounds__(256, 3) void qkv_gemm_mfma(
    const unsigned short* __restrict__ xb, const unsigned short* __restrict__ Wt,
    const float* __restrict__ bq, const float* __restrict__ bk, const float* __restrict__ bv,
    const float* __restrict__ cosb, const float* __restrict__ sinb,
    unsigned short* __restrict__ q, unsigned short* __restrict__ k, unsigned short* __restrict__ v)
{
    __shared__ __attribute__((aligned(16))) short As[128 * 64];
    __shared__ __attribute__((aligned(16))) short Bs[128 * 64];
    const int lane = threadIdx.x & 63;
    const int w = threadIdx.x >> 6;
    const int w1 = w >> 1;
    const int m0 = blockIdx.y * 128;
    const int n0 = blockIdx.x * 128;
    const int lm = lane & 15;
    const int q8 = lane >> 4;

    int mrow[4], nrow[4];
#pragma unroll
    for (int i = 0; i < 4; ++i) {
        mrow[i] = (w & 1) * 64 + i * 16;
        nrow[i] = w1 * 32 + (i & 1) * 16 + (i >> 1) * 64;   // d and d^64 at in^2
    }

    f32x4 acc[4][4];
#pragma unroll
    for (int im = 0; im < 4; ++im)
#pragma unroll
        for (int in = 0; in < 4; ++in) acc[im][in] = {0.f, 0.f, 0.f, 0.f};

    gemm_core_128x128x64(xb, Wt, As, Bs, m0, n0, mrow, nrow, acc);

    unsigned short* dst; const float* bias; int ldD, off, mode;
    if (n0 < 2048)      { dst = q; bias = bq; ldD = 2048; off = n0;        mode = 0; }
    else if (n0 < 2560) { dst = k; bias = bk; ldD = 512;  off = n0 - 2048; mode = 1; }
    else                { dst = v; bias = bv; ldD = 512;  off = n0 - 2560; mode = 2; }

    float bv_[4];
#pragma unroll
    for (int in = 0; in < 4; ++in) bv_[in] = bias[off + nrow[in] + lm];

#pragma unroll
    for (int im = 0; im < 4; ++im) {
        int rowbase = m0 + mrow[im] + q8 * 4;
        float t[4][4];                      // [in][r], biased pre-rope values
#pragma unroll
        for (int in = 0; in < 4; ++in)
#pragma unroll
            for (int r = 0; r < 4; ++r) t[in][r] = acc[im][in][r] + bv_[in];
        if (mode < 2) {                     // rope (q and k)
#pragma unroll
            for (int in = 0; in < 4; ++in) {
                int d = nrow[in] + lm;
                float sgn = (in < 2) ? -1.f : 1.f;   // d<64 <=> in<2
#pragma unroll
                for (int r = 0; r < 4; ++r) {
                    int row = rowbase + r;
                    float c = cosb[row * HD + d];
                    float s = sinb[row * HD + d];
                    float o = c * t[in][r] + sgn * s * t[in ^ 2][r];
                    if (mode == 0) o *= QSCALE;
                    dst[(size_t)row * ldD + off + d] = f2bf(o);
                }
            }
        } else {                            // v: bias only
#pragma unroll
            for (int in = 0; in < 4; ++in)
#pragma unroll
                for (int r = 0; r < 4; ++r)
                    dst[(size_t)(rowbase + r) * ldD + off + nrow[in] + lm] = f2bf(t[in][r]);
        }
    }
}

__global__ __launch_bounds__(256, 3) void out_gemm_mfma(
    const unsigned short* __restrict__ yb, const unsigned short* __restrict__ Wot,
    float* __restrict__ Cout)
{
    __shared__ __attribute__((aligned(16))) short As[128 * 64];
    __shared__ __attribute__((aligned(16))) short Bs[128 * 64];
    const int lane = threadIdx.x & 63;
    const int w = threadIdx.x >> 6;
    const int m0 = blockIdx.y * 128;
    const int n0 = blockIdx.x * 128;
    const int lm = lane & 15;
    const int q8 = lane >> 4;

    int mrow[4], nrow[4];
#pragma unroll
    for (int i = 0; i < 4; ++i) {
        mrow[i] = (w & 1) * 64 + i * 16;
        nrow[i] = (w >> 1) * 64 + i * 16;
    }

    f32x4 acc[4][4];
#pragma unroll
    for (int im = 0; im < 4; ++im)
#pragma unroll
        for (int in = 0; in < 4; ++in) acc[im][in] = {0.f, 0.f, 0.f, 0.f};

    gemm_core_128x128x64(yb, Wot, As, Bs, m0, n0, mrow, nrow, acc);

#pragma unroll
    for (int im = 0; im < 4; ++im)
#pragma unroll
        for (int in = 0; in < 4; ++in)
#pragma unroll
            for (int r = 0; r < 4; ++r) {
                int row = m0 + mrow[im] + q8 * 4 + r;
                Cout[(size_t)row * CC + n0 + nrow[in] + lm] = acc[im][in][r];
            }
}

// ---------------------------------------------------------------------------
// V transpose: v[b][t][g*128+d] bf16 -> vt[(b*4+g)*128+d][t] bf16
// ---------------------------------------------------------------------------
__global__ __launch_bounds__(256) void vtrans_kernel(
    const unsigned short* __restrict__ v, unsigned short* __restrict__ vt)
{
    __shared__ unsigned short tile[64][68];
    int bg = blockIdx.z;           // b*4+g
    int b = bg >> 2, g = bg & 3;
    int t0 = blockIdx.x * 64;
    int d0 = blockIdx.y * 64;
    int tx = threadIdx.x & 15, ty = threadIdx.x >> 4;
#pragma unroll
    for (int i = 0; i < 4; ++i) {
        int r = ty + i * 16;
        ushort4 v4 = *(const ushort4*)&v[(size_t)(b * TT + t0 + r) * (HKK * HD) + g * HD + d0 + tx * 4];
        tile[r][tx * 4 + 0] = v4.x;
        tile[r][tx * 4 + 1] = v4.y;
        tile[r][tx * 4 + 2] = v4.z;
        tile[r][tx * 4 + 3] = v4.w;
    }
    __syncthreads();
#pragma unroll
    for (int i = 0; i < 4; ++i) {
        int r = ty + i * 16;   // d-local
        int c = tx * 4;        // t-local
        ushort4 o;
        o.x = tile[c + 0][r];
        o.y = tile[c + 1][r];
        o.z = tile[c + 2][r];
        o.w = tile[c + 3][r];
        *(ushort4*)&vt[(size_t)(bg * HD + d0 + r) * TT + t0 + c] = o;
    }
}

// ---------------------------------------------------------------------------
// Work-item table for causal load balance.  24 items per (b,h):
//   qi 0..7  : unsplit tiles (hf=2), 2qi+2 KV-iters (2..16)
//   qi 8..15 : split into two KV halves (hf=0: j in [0,qi+1), hf=1:
//              [qi+1,2qi+2)), qi+1 iters each (9..16)
// Ordered so dispatch tiers (yb 0-7, 8-15, 16-23) form per-CU triples each
// summing to exactly 34 iter-units -> balanced makespan with all 768 blocks
// co-resident (3 blocks/CU: 3 x 54272 B LDS = 162816 <= 163840).
// ---------------------------------------------------------------------------
static __device__ const signed char QI_T[24] = {
    15, 7, 14, 14, 13, 6, 12, 11,
    15, 13, 12, 10, 10, 9, 11, 5,
    0, 1, 2, 3, 8, 4, 8, 9
};
static __device__ const signed char HF_T[24] = {
    0, 2, 0, 1, 1, 2, 1, 1,
    1, 0, 0, 0, 1, 0, 0, 2,
    2, 2, 2, 2, 0, 2, 1, 1
};

// ---------------------------------------------------------------------------
// MFMA flash attention, BR=128, 512 threads (8 waves); wave w owns 16 q-rows.
// BC=64.  S computed transposed (S^T = K·Q^T): softmax state is per-lane
// scalar, 2 shuffles for max, per-lane partial l.  q is pre-scaled (QSCALE,
// exp2 domain) and pre-roped by qkv_gemm.
// Split chunks (hf<2) write per-chunk NORMALIZED partials Ô = O~/l (f32, into
// d_out scratch) plus one scalar s = l·2^m per row; combine_kernel merges
// O = (s0·Ô0 + s1·Ô1)/(s0+s1) — identical math to online softmax.
// Unsplit chunks keep the LDS-staged coalesced bf16 y epilogue.
// ---------------------------------------------------------------------------
__global__ __launch_bounds__(512, 6) void flash_mfma(
    const unsigned short* __restrict__ q, const unsigned short* __restrict__ k,
    const unsigned short* __restrict__ vt, unsigned short* __restrict__ y,
    float* __restrict__ po, float* __restrict__ sb)
{
    // Ks 64x136 | Vs 128x72 | Ps 8x16x72   (27136 shorts = 54272 B)
    __shared__ __attribute__((aligned(16))) short SM[27136];
    short* Ks = SM;                 // 8704 shorts
    short* Vs = SM + 8704;          // 9216 shorts
    short* Ps = SM + 17920;         // 9216 shorts

    const int tid = threadIdx.x;
    const int lane = tid & 63;
    const int w = tid >> 6;               // 0..7
    const int lm = lane & 15;
    const int q8 = lane >> 4;
    const int bh = blockIdx.x;            // 0..31
    const int b = bh >> 4, h = bh & 15, g = h >> 2;
    const int yb_ = blockIdx.y;           // 0..23
    const int qi = QI_T[yb_];
    const int hf = HF_T[yb_];             // 0/1 = split half, 2 = unsplit
    const int q0 = qi * 128;
    const int wrow = w * 16;
    const int jdiag = 2 * qi + (w >> 2);  // this wave's diagonal tile
    int j0, jend;
    if (hf == 2)      { j0 = 0;      jend = 2 * qi + 2; }
    else if (hf == 0) { j0 = 0;      jend = qi + 1; }
    else              { j0 = qi + 1; jend = 2 * qi + 2; }

    // Q fragments (pre-scaled + roped by qkv_gemm).  B-operand of S^T = K·Q^T.
    bf16x8 qf[4];
#pragma unroll
    for (int ks = 0; ks < 4; ++ks)
        qf[ks] = *(const bf16x8*)&q[(size_t)(b * TT + q0 + wrow + lm) * CC
                                    + h * HD + ks * 32 + q8 * 8];

    f32x4 o_acc[8];
#pragma unroll
    for (int nt = 0; nt < 8; ++nt) o_acc[nt] = {0.f, 0.f, 0.f, 0.f};
    float m_i = -1e30f;                   // row lm's running max (exp2 domain)
    float l_i = 0.f;                      // per-lane PARTIAL row sum

    // staging geometry: 1024 16B-chunks each for K and V over 512 threads
    int ktok[2], ke8[2], vd[2], vt8[2];
#pragma unroll
    for (int i = 0; i < 2; ++i) {
        int f = tid + i * 512;
        ktok[i] = f >> 4; ke8[i] = (f & 15) * 8;
        vd[i]   = f >> 3; vt8[i] = (f & 7) * 8;
    }
    const unsigned short* kbase = k + (size_t)(b * TT) * (HKK * HD) + g * HD;
    const unsigned short* vbase = vt + (size_t)((b * 4 + g) * HD) * TT;

    uint4 kreg[2], vreg[2];
#pragma unroll
    for (int i = 0; i < 2; ++i) {
        kreg[i] = *(const uint4*)&kbase[(size_t)(j0 * 64 + ktok[i]) * (HKK * HD) + ke8[i]];
        vreg[i] = *(const uint4*)&vbase[(size_t)vd[i] * TT + j0 * 64 + vt8[i]];
    }

    short* Pw = Ps + w * 16 * 72;
    const int mrow = (w & 3) * 16 + lm;   // diagonal-tile row offset

    for (int j = j0; j < jend; ++j) {
        __syncthreads();                 // prev iter's K/V LDS reads complete
#pragma unroll
        for (int i = 0; i < 2; ++i) {
            *(uint4*)&Ks[ktok[i] * 136 + ke8[i]] = kreg[i];
            *(uint4*)&Vs[vd[i] * 72 + vt8[i]]    = vreg[i];
        }
        __syncthreads();                 // tiles visible
        if (j + 1 < jend) {              // prefetch next tile (uniform branch)
#pragma unroll
            for (int i = 0; i < 2; ++i) {
                kreg[i] = *(const uint4*)&kbase[(size_t)((j + 1) * 64 + ktok[i]) * (HKK * HD) + ke8[i]];
                vreg[i] = *(const uint4*)&vbase[(size_t)vd[i] * TT + (j + 1) * 64 + vt8[i]];
            }
        }

        if (j <= jdiag) {
            // S^T = K·Q^T : C-layout col=lm -> qrow, row=q8*4+r -> token
            f32x4 sacc[4];
#pragma unroll
            for (int ct = 0; ct < 4; ++ct) {
                sacc[ct] = {0.f, 0.f, 0.f, 0.f};
#pragma unroll
                for (int ks = 0; ks < 4; ++ks) {
                    bf16x8 kf = *(const bf16x8*)&Ks[(ct * 16 + lm) * 136 + ks * 32 + q8 * 8];
                    sacc[ct] = __builtin_amdgcn_mfma_f32_16x16x32_bf16(kf, qf[ks], sacc[ct], 0, 0, 0);
                }
            }
            if (j == jdiag) {            // causal mask (only diagonal tile)
#pragma unroll
                for (int ct = 0; ct < 4; ++ct)
#pragma unroll
                    for (int r = 0; r < 4; ++r)
                        if (ct * 16 + q8 * 4 + r > mrow) sacc[ct][r] = -1e30f;
            }
            // row max: 15 in-lane + 2 cross-lane
            float tmax = fmaxf(
                fmaxf(fmaxf(fmaxf(sacc[0][0], sacc[0][1]), fmaxf(sacc[0][2], sacc[0][3])),
                      fmaxf(fmaxf(sacc[1][0], sacc[1][1]), fmaxf(sacc[1][2], sacc[1][3]))),
                fmaxf(fmaxf(fmaxf(sacc[2][0], sacc[2][1]), fmaxf(sacc[2][2], sacc[2][3])),
                      fmaxf(fmaxf(sacc[3][0], sacc[3][1]), fmaxf(sacc[3][2], sacc[3][3]))));
            tmax = fmaxf(tmax, __shfl_xor(tmax, 16));
            tmax = fmaxf(tmax, __shfl_xor(tmax, 32));
            float m_new = fmaxf(m_i, tmax);
            float alpha = exp2f(m_i - m_new);
            m_i = m_new;

            float ps = 0.f;
#pragma unroll
            for (int ct = 0; ct < 4; ++ct) {
                ushort4 pp;
                float p0 = exp2f(sacc[ct][0] - m_new);
                float p1 = exp2f(sacc[ct][1] - m_new);
                float p2 = exp2f(sacc[ct][2] - m_new);
                float p3 = exp2f(sacc[ct][3] - m_new);
                ps += (p0 + p1) + (p2 + p3);
                pp.x = f2bf(p0); pp.y = f2bf(p1); pp.z = f2bf(p2); pp.w = f2bf(p3);
                *(ushort4*)&Pw[lm * 72 + ct * 16 + q8 * 4] = pp;
            }
            l_i = l_i * alpha + ps;      // per-lane partial; alpha row-uniform

            float a0 = __shfl(alpha, q8 * 4 + 0);
            float a1 = __shfl(alpha, q8 * 4 + 1);
            float a2 = __shfl(alpha, q8 * 4 + 2);
            float a3 = __shfl(alpha, q8 * 4 + 3);
#pragma unroll
            for (int nt = 0; nt < 8; ++nt) {
                o_acc[nt][0] *= a0;
                o_acc[nt][1] *= a1;
                o_acc[nt][2] *= a2;
                o_acc[nt][3] *= a3;
            }

            // O += P·V
#pragma unroll
            for (int ks2 = 0; ks2 < 2; ++ks2) {
                bf16x8 pf = *(const bf16x8*)&Pw[lm * 72 + ks2 * 32 + q8 * 8];
#pragma unroll
                for (int nt = 0; nt < 8; ++nt) {
                    bf16x8 vf = *(const bf16x8*)&Vs[(nt * 16 + lm) * 72 + ks2 * 32 + q8 * 8];
                    o_acc[nt] = __builtin_amdgcn_mfma_f32_16x16x32_bf16(pf, vf, o_acc[nt], 0, 0, 0);
                }
            }
        }
    }

    // finalize l: sum partials over the 4 q8 groups, fetch per-o_acc-row
    float lf = l_i;
    lf += __shfl_xor(lf, 16);
    lf += __shfl_xor(lf, 32);
    float inv[4];
#pragma unroll
    for (int r = 0; r < 4; ++r) inv[r] = 1.f / __shfl(lf, q8 * 4 + r);

    if (hf == 2) {
        // Epilogue: stage O in LDS (128 rows x stride 136, over Ks+Vs space),
        // read back b128, store coalesced dwordx4.
        __syncthreads();                   // all waves done with Ks/Vs/Ps
        short* Es = SM;                    // 128*136 = 17408 shorts
#pragma unroll
        for (int nt = 0; nt < 8; ++nt)
#pragma unroll
            for (int r = 0; r < 4; ++r)
                Es[(wrow + q8 * 4 + r) * 136 + nt * 16 + lm] = (short)f2bf(o_acc[nt][r] * inv[r]);
        __syncthreads();
#pragma unroll
        for (int i = 0; i < 4; ++i) {
            int f = tid + i * 512;             // 0..2047
            int row = f >> 4, ch = f & 15;
            uint4 t = *(const uint4*)&Es[row * 136 + ch * 8];
            *(uint4*)&y[(size_t)(b * TT + q0 + row) * CC + h * HD + ch * 8] = t;
        }
    } else {
        // Split-chunk epilogue: normalized Ô (f32) + per-row s = l·2^m.
        const int pi = ((bh << 3) + (qi - 8)) * 2 + hf;
        if (lane < 16) sb[pi * 128 + wrow + lane] = lf * exp2f(m_i);
        float* pb = po + (size_t)pi * 16384;
#pragma unroll
        for (int nt = 0; nt < 8; ++nt)
#pragma unroll
            for (int r = 0; r < 4; ++r)
                pb[(wrow + q8 * 4 + r) * 128 + nt * 16 + lm] = o_acc[nt][r] * inv[r];
    }
}

// ---------------------------------------------------------------------------
// Merge the two KV-half partials of split tiles (qi 8..15):
//   O = (s0·Ô0 + s1·Ô1)/(s0+s1),  then bf16 -> y.
// ---------------------------------------------------------------------------
__global__ __launch_bounds__(256) void combine_kernel(
    const float* __restrict__ po, const float* __restrict__ sb,
    unsigned short* __restrict__ y)
{
    const int bh = blockIdx.x;             // 0..31
    const int b = bh >> 4, h = bh & 15;
    const int qi = 8 + blockIdx.y;         // 8..15
    const int p0 = ((bh << 3) + (qi - 8)) * 2;
    const int t = threadIdx.x;
    const int row = t >> 1, d0 = (t & 1) * 64;
    float s0 = sb[p0 * 128 + row];
    float s1 = sb[(p0 + 1) * 128 + row];
    float w0 = s0 / (s0 + s1);
    float w1 = 1.f - w0;
    const float* a = &po[(size_t)p0 * 16384 + row * 128 + d0];
    const float* c = &po[(size_t)(p0 + 1) * 16384 + row * 128 + d0];
    unsigned short* yr = &y[(size_t)(b * TT + qi * 128 + row) * CC + h * HD + d0];
#pragma unroll
    for (int i = 0; i < 64; i += 4) {
        float4 xa = *(const float4*)&a[i];
        float4 xc = *(const float4*)&c[i];
        ushort4 o;
        o.x = f2bf(w0 * xa.x + w1 * xc.x);
        o.y = f2bf(w0 * xa.y + w1 * xc.y);
        o.z = f2bf(w0 * xa.z + w1 * xc.z);
        o.w = f2bf(w0 * xa.w + w1 * xc.w);
        *(ushort4*)&yr[i] = o;
    }
}

// ---------------------------------------------------------------------------
extern "C" void kernel_launch(void* const* d_in, const int* in_sizes, int n_in,
                              void* d_out, int out_size, void* d_ws, size_t ws_size,
                              hipStream_t stream) {
    const float* x    = (const float*)d_in[0];
    const float* cosb = (const float*)d_in[1];
    const float* sinb = (const float*)d_in[2];
    const float* Wq   = (const float*)d_in[3];
    const float* bq   = (const float*)d_in[4];
    const float* Wk   = (const float*)d_in[5];
    const float* bk   = (const float*)d_in[6];
    const float* Wv   = (const float*)d_in[7];
    const float* bv   = (const float*)d_in[8];
    const float* Wo   = (const float*)d_in[9];
    float* out = (float*)d_out;

    // workspace (all bf16 as ushort):
    // xb[4096*2048] Wt[3072*2048] Wot[2048*2048] qb[4096*2048]
    // kb[4096*512] vb[4096*512] vtb[1024*2048] yb[4096*2048]  = 83.9 MB
    unsigned short* xb  = (unsigned short*)d_ws;
    unsigned short* Wt  = xb  + (size_t)MM * CC;
    unsigned short* Wot = Wt  + (size_t)3072 * 2048;
    unsigned short* qb  = Wot + (size_t)2048 * 2048;
    unsigned short* kb  = qb  + (size_t)MM * CC;
    unsigned short* vb  = kb  + (size_t)MM * (HKK * HD);
    unsigned short* vtb = vb  + (size_t)MM * (HKK * HD);
    unsigned short* ybf = vtb + (size_t)BB * HKK * HD * TT;

    // Scratch aliases for the split-KV flash path (no new workspace):
    //  - po: 512 partial tiles x 128x128 f32 = 33.55 MB == d_out size exactly
    //        (d_out is dead until out_gemm overwrites every element).
    //  - sb: 512x128 f32 row-scalars s = l*2^m, over dead xb (dead after qkv).
    float* po = (float*)d_out;
    float* sbuf = (float*)xb;

    cast_x_kernel<<<dim3((MM * CC) / 2048), 256, 0, stream>>>(x, xb);
    wtrans_kernel<<<dim3(32, 32, 4), 256, 0, stream>>>(Wq, Wk, Wv, Wo, Wt, Wot);
    qkv_gemm_mfma<<<dim3(3072 / 128, MM / 128), 256, 0, stream>>>(
        xb, Wt, bq, bk, bv, cosb, sinb, qb, kb, vb);
    vtrans_kernel<<<dim3(TT / 64, HD / 64, BB * HKK), 256, 0, stream>>>(vb, vtb);
    flash_mfma<<<dim3(BB * HH, 24), 512, 0, stream>>>(qb, kb, vtb, ybf, po, sbuf);
    combine_kernel<<<dim3(BB * HH, 8), 256, 0, stream>>>(po, sbuf, ybf);
    out_gemm_mfma<<<dim3(CC / 128, MM / 128), 256, 0, stream>>>(ybf, Wot, out);
}

// Round 2
// 368.051 us; speedup vs baseline: 1.3642x; 1.3642x over previous
//
#include <hip/hip_runtime.h>
#include <math.h>

// Problem constants
#define BB 2
#define TT 2048
#define CC 2048
#define HH 16
#define HKK 4
#define HD 128
#define MM (BB*TT)          // 4096 rows

typedef short bf16x8 __attribute__((ext_vector_type(8)));
typedef float f32x4 __attribute__((ext_vector_type(4)));

#define GLOBAL_AS(p) ((const __attribute__((address_space(1))) void*)(p))
#define LDS_AS(p)    ((__attribute__((address_space(3))) void*)(p))

__device__ __forceinline__ unsigned short f2bf(float f) {
    unsigned u = __float_as_uint(f);
    u += 0x7fff + ((u >> 16) & 1);          // round-to-nearest-even
    return (unsigned short)(u >> 16);
}
__device__ __forceinline__ float bf2f(unsigned short h) {
    return __uint_as_float(((unsigned)h) << 16);
}

// softmax scale 1/sqrt(128) * log2(e), folded into q at projection time
#define QSCALE (0.08838834764831845f * 1.44269504088896340736f)

// ---------------------------------------------------------------------------
// cast x (f32 -> bf16), 8 elements/thread
// ---------------------------------------------------------------------------
__global__ __launch_bounds__(256) void cast_x_kernel(
    const float* __restrict__ x, unsigned short* __restrict__ xb)
{
    size_t i = ((size_t)blockIdx.x * 256 + threadIdx.x) * 8;
    float4 a = *(const float4*)&x[i];
    float4 b = *(const float4*)&x[i + 4];
    uint4 r;
    r.x = f2bf(a.x) | ((unsigned)f2bf(a.y) << 16);
    r.y = f2bf(a.z) | ((unsigned)f2bf(a.w) << 16);
    r.z = f2bf(b.x) | ((unsigned)f2bf(b.y) << 16);
    r.w = f2bf(b.z) | ((unsigned)f2bf(b.w) << 16);
    *(uint4*)&xb[i] = r;
}

// ---------------------------------------------------------------------------
// Weight transpose+cast: W[K][N] f32 -> Wt[N][K] bf16.
// ---------------------------------------------------------------------------
__global__ __launch_bounds__(256) void wtrans_kernel(
    const float* __restrict__ Wq, const float* __restrict__ Wk,
    const float* __restrict__ Wv, const float* __restrict__ Wo,
    unsigned short* __restrict__ Wt, unsigned short* __restrict__ Wot)
{
    __shared__ float tile[64][65];
    int z = blockIdx.z;
    const float* src; unsigned short* dst; int ldW, nmax, noff;
    if (z == 0)      { src = Wq; dst = Wt;  ldW = 2048; nmax = 2048; noff = 0; }
    else if (z == 1) { src = Wk; dst = Wt;  ldW = 512;  nmax = 512;  noff = 2048; }
    else if (z == 2) { src = Wv; dst = Wt;  ldW = 512;  nmax = 512;  noff = 2560; }
    else             { src = Wo; dst = Wot; ldW = 2048; nmax = 2048; noff = 0; }
    int n0 = blockIdx.y * 64;
    if (n0 >= nmax) return;
    int k0 = blockIdx.x * 64;
    int tx = threadIdx.x & 15, ty = threadIdx.x >> 4;
#pragma unroll
    for (int i = 0; i < 4; ++i) {
        int r = ty + i * 16;
        float4 v4 = *(const float4*)&src[(size_t)(k0 + r) * ldW + n0 + tx * 4];
        tile[r][tx * 4 + 0] = v4.x;
        tile[r][tx * 4 + 1] = v4.y;
        tile[r][tx * 4 + 2] = v4.z;
        tile[r][tx * 4 + 3] = v4.w;
    }
    __syncthreads();
#pragma unroll
    for (int i = 0; i < 4; ++i) {
        int r = ty + i * 16;     // n-local
        int c = tx * 4;          // k-local
        ushort4 o;
        o.x = f2bf(tile[c + 0][r]);
        o.y = f2bf(tile[c + 1][r]);
        o.z = f2bf(tile[c + 2][r]);
        o.w = f2bf(tile[c + 3][r]);
        *(ushort4*)&dst[(size_t)(noff + n0 + r) * 2048 + k0 + c] = o;
    }
}

// ---------------------------------------------------------------------------
// MFMA GEMM core 128x128x64, 4 waves, 16x16x32 bf16, global_load_lds staging,
// XOR-swizzled k-chunks.  mrow/nrow give each wave's 4 m/n tile bases.
// ---------------------------------------------------------------------------
__device__ __forceinline__ void gemm_core_128x128x64(
    const unsigned short* __restrict__ A, const unsigned short* __restrict__ B,
    short* As, short* Bs, int m0, int n0,
    const int* mrow, const int* nrow, f32x4 (&acc)[4][4])
{
    const int tid = threadIdx.x;
    const int lane = tid & 63;
    const int w = tid >> 6;
    const int lm = lane & 15;
    const int q8 = lane >> 4;
    const int lrow = lane >> 3;            // 0..7 within an instr's 8 rows
    const int lchunk = lane & 7;           // lane's LDS chunk slot

    for (int kt = 0; kt < CC; kt += 64) {
        __syncthreads();                   // prev iter frag reads complete
#pragma unroll
        for (int jj = 0; jj < 4; ++jj) {
            int rA = w * 32 + jj * 8 + lrow;
            int cA = ((lchunk ^ (rA & 7)) << 3);
            __builtin_amdgcn_global_load_lds(
                GLOBAL_AS(&A[(size_t)(m0 + rA) * CC + kt + cA]),
                LDS_AS(&As[(w * 32 + jj * 8) * 64]), 16, 0, 0);
            __builtin_amdgcn_global_load_lds(
                GLOBAL_AS(&B[(size_t)(n0 + rA) * CC + kt + cA]),
                LDS_AS(&Bs[(w * 32 + jj * 8) * 64]), 16, 0, 0);
        }
        __syncthreads();                   // vmcnt drained -> tiles visible
#pragma unroll
        for (int ksi = 0; ksi < 2; ++ksi) {
            bf16x8 af[4], bfr[4];
#pragma unroll
            for (int i = 0; i < 4; ++i) {
                int xo = (((ksi * 4 + q8) ^ (lm & 7)) << 3);
                af[i]  = *(const bf16x8*)&As[(mrow[i] + lm) * 64 + xo];
                bfr[i] = *(const bf16x8*)&Bs[(nrow[i] + lm) * 64 + xo];
            }
#pragma unroll
            for (int im = 0; im < 4; ++im)
#pragma unroll
                for (int in = 0; in < 4; ++in)
                    acc[im][in] = __builtin_amdgcn_mfma_f32_16x16x32_bf16(af[im], bfr[in], acc[im][in], 0, 0, 0);
        }
    }
}

// ---------------------------------------------------------------------------
// QKV GEMM with fused bias + RoPE + q-scale.  Each 128-col block is exactly
// one head (HD=128).  Wave n-tiles remapped to {w1*32+(in&1)*16+(in>>1)*64}
// so d and d^64 are in the SAME lane at in^2 -> in-register RoPE.
// ---------------------------------------------------------------------------
__global__ __launch_bounds__(256, 3) void qkv_gemm_mfma(
    const unsigned short* __restrict__ xb, const unsigned short* __restrict__ Wt,
    const float* __restrict__ bq, const float* __restrict__ bk, const float* __restrict__ bv,
    const float* __restrict__ cosb, const float* __restrict__ sinb,
    unsigned short* __restrict__ q, unsigned short* __restrict__ k, unsigned short* __restrict__ v)
{
    __shared__ __attribute__((aligned(16))) short As[128 * 64];
    __shared__ __attribute__((aligned(16))) short Bs[128 * 64];
    const int lane = threadIdx.x & 63;
    const int w = threadIdx.x >> 6;
    const int w1 = w >> 1;
    const int m0 = blockIdx.y * 128;
    const int n0 = blockIdx.x * 128;
    const int lm = lane & 15;
    const int q8 = lane >> 4;

    int mrow[4], nrow[4];
#pragma unroll
    for (int i = 0; i < 4; ++i) {
        mrow[i] = (w & 1) * 64 + i * 16;
        nrow[i] = w1 * 32 + (i & 1) * 16 + (i >> 1) * 64;   // d and d^64 at in^2
    }

    f32x4 acc[4][4];
#pragma unroll
    for (int im = 0; im < 4; ++im)
#pragma unroll
        for (int in = 0; in < 4; ++in) acc[im][in] = {0.f, 0.f, 0.f, 0.f};

    gemm_core_128x128x64(xb, Wt, As, Bs, m0, n0, mrow, nrow, acc);

    unsigned short* dst; const float* bias; int ldD, off, mode;
    if (n0 < 2048)      { dst = q; bias = bq; ldD = 2048; off = n0;        mode = 0; }
    else if (n0 < 2560) { dst = k; bias = bk; ldD = 512;  off = n0 - 2048; mode = 1; }
    else                { dst = v; bias = bv; ldD = 512;  off = n0 - 2560; mode = 2; }

    float bv_[4];
#pragma unroll
    for (int in = 0; in < 4; ++in) bv_[in] = bias[off + nrow[in] + lm];

#pragma unroll
    for (int im = 0; im < 4; ++im) {
        int rowbase = m0 + mrow[im] + q8 * 4;
        float t[4][4];                      // [in][r], biased pre-rope values
#pragma unroll
        for (int in = 0; in < 4; ++in)
#pragma unroll
            for (int r = 0; r < 4; ++r) t[in][r] = acc[im][in][r] + bv_[in];
        if (mode < 2) {                     // rope (q and k)
#pragma unroll
            for (int in = 0; in < 4; ++in) {
                int d = nrow[in] + lm;
                float sgn = (in < 2) ? -1.f : 1.f;   // d<64 <=> in<2
#pragma unroll
                for (int r = 0; r < 4; ++r) {
                    int row = rowbase + r;
                    float c = cosb[row * HD + d];
                    float s = sinb[row * HD + d];
                    float o = c * t[in][r] + sgn * s * t[in ^ 2][r];
                    if (mode == 0) o *= QSCALE;
                    dst[(size_t)row * ldD + off + d] = f2bf(o);
                }
            }
        } else {                            // v: bias only
#pragma unroll
            for (int in = 0; in < 4; ++in)
#pragma unroll
                for (int r = 0; r < 4; ++r)
                    dst[(size_t)(rowbase + r) * ldD + off + nrow[in] + lm] = f2bf(t[in][r]);
        }
    }
}

__global__ __launch_bounds__(256, 3) void out_gemm_mfma(
    const unsigned short* __restrict__ yb, const unsigned short* __restrict__ Wot,
    float* __restrict__ Cout)
{
    __shared__ __attribute__((aligned(16))) short As[128 * 64];
    __shared__ __attribute__((aligned(16))) short Bs[128 * 64];
    const int lane = threadIdx.x & 63;
    const int w = threadIdx.x >> 6;
    const int m0 = blockIdx.y * 128;
    const int n0 = blockIdx.x * 128;
    const int lm = lane & 15;
    const int q8 = lane >> 4;

    int mrow[4], nrow[4];
#pragma unroll
    for (int i = 0; i < 4; ++i) {
        mrow[i] = (w & 1) * 64 + i * 16;
        nrow[i] = (w >> 1) * 64 + i * 16;
    }

    f32x4 acc[4][4];
#pragma unroll
    for (int im = 0; im < 4; ++im)
#pragma unroll
        for (int in = 0; in < 4; ++in) acc[im][in] = {0.f, 0.f, 0.f, 0.f};

    gemm_core_128x128x64(yb, Wot, As, Bs, m0, n0, mrow, nrow, acc);

#pragma unroll
    for (int im = 0; im < 4; ++im)
#pragma unroll
        for (int in = 0; in < 4; ++in)
#pragma unroll
            for (int r = 0; r < 4; ++r) {
                int row = m0 + mrow[im] + q8 * 4 + r;
                Cout[(size_t)row * CC + n0 + nrow[in] + lm] = acc[im][in][r];
            }
}

// ---------------------------------------------------------------------------
// V transpose: v[b][t][g*128+d] bf16 -> vt[(b*4+g)*128+d][t] bf16
// ---------------------------------------------------------------------------
__global__ __launch_bounds__(256) void vtrans_kernel(
    const unsigned short* __restrict__ v, unsigned short* __restrict__ vt)
{
    __shared__ unsigned short tile[64][68];
    int bg = blockIdx.z;           // b*4+g
    int b = bg >> 2, g = bg & 3;
    int t0 = blockIdx.x * 64;
    int d0 = blockIdx.y * 64;
    int tx = threadIdx.x & 15, ty = threadIdx.x >> 4;
#pragma unroll
    for (int i = 0; i < 4; ++i) {
        int r = ty + i * 16;
        ushort4 v4 = *(const ushort4*)&v[(size_t)(b * TT + t0 + r) * (HKK * HD) + g * HD + d0 + tx * 4];
        tile[r][tx * 4 + 0] = v4.x;
        tile[r][tx * 4 + 1] = v4.y;
        tile[r][tx * 4 + 2] = v4.z;
        tile[r][tx * 4 + 3] = v4.w;
    }
    __syncthreads();
#pragma unroll
    for (int i = 0; i < 4; ++i) {
        int r = ty + i * 16;   // d-local
        int c = tx * 4;        // t-local
        ushort4 o;
        o.x = tile[c + 0][r];
        o.y = tile[c + 1][r];
        o.z = tile[c + 2][r];
        o.w = tile[c + 3][r];
        *(ushort4*)&vt[(size_t)(bg * HD + d0 + r) * TT + t0 + c] = o;
    }
}

// ---------------------------------------------------------------------------
// Work-item table for causal load balance.  24 items per (b,h):
//   qi 0..7  : unsplit tiles (hf=2), 2qi+2 KV-iters (2..16)
//   qi 8..15 : split into two KV halves (hf=0: j in [0,qi+1), hf=1:
//              [qi+1,2qi+2)), qi+1 iters each (9..16)
// Ordered so dispatch tiers (yb 0-7, 8-15, 16-23) form per-CU triples each
// summing to exactly 34 iter-units -> balanced makespan with all 768 blocks
// co-resident (3 blocks/CU: 3 x 53248 B LDS = 159744 <= 163840).
// ---------------------------------------------------------------------------
static __device__ const signed char QI_T[24] = {
    15, 7, 14, 14, 13, 6, 12, 11,
    15, 13, 12, 10, 10, 9, 11, 5,
    0, 1, 2, 3, 8, 4, 8, 9
};
static __device__ const signed char HF_T[24] = {
    0, 2, 0, 1, 1, 2, 1, 1,
    1, 0, 0, 0, 1, 0, 0, 2,
    2, 2, 2, 2, 0, 2, 1, 1
};

// ---------------------------------------------------------------------------
// MFMA flash attention, BR=128, 512 threads (8 waves); wave w owns 16 q-rows.
// BC=64.  S computed transposed (S^T = K·Q^T): softmax state is per-lane
// scalar, 2 shuffles for max, per-lane partial l.  q is pre-scaled (QSCALE,
// exp2 domain) and pre-roped by qkv_gemm.
// Split chunks (hf<2) write per-chunk NORMALIZED partials Ô = O~/l (f32, into
// d_out scratch) plus one scalar s = l·2^m per row; combine_kernel merges
// O = (s0·Ô0 + s1·Ô1)/(s0+s1) — identical math to online softmax.
// Unsplit chunks keep the LDS-staged coalesced bf16 y epilogue.
// NOTE: __launch_bounds__(512, 4) — NOT 6.  (512,6) caps regs at ~85 and
// spills o_acc to scratch: r1 measured VGPR 60->40, FETCH 33->453 MB,
// WRITE 104->438 MB (symmetric spill round-trips), dur 155->265 us.
// Residency is LDS-limited instead: 53248 B/block -> 3 blocks/CU.
// ---------------------------------------------------------------------------
__global__ __launch_bounds__(512, 4) void flash_mfma(
    const unsigned short* __restrict__ q, const unsigned short* __restrict__ k,
    const unsigned short* __restrict__ vt, unsigned short* __restrict__ y,
    float* __restrict__ po, float* __restrict__ sb)
{
    // Ks 64x136 | Vs 128x72 | Ps 8x16x68   (26624 shorts = 53248 B)
    __shared__ __attribute__((aligned(16))) short SM[26624];
    short* Ks = SM;                 // 8704 shorts
    short* Vs = SM + 8704;          // 9216 shorts
    short* Ps = SM + 17920;         // 8704 shorts

    const int tid = threadIdx.x;
    const int lane = tid & 63;
    const int w = tid >> 6;               // 0..7
    const int lm = lane & 15;
    const int q8 = lane >> 4;
    const int bh = blockIdx.x;            // 0..31
    const int b = bh >> 4, h = bh & 15, g = h >> 2;
    const int yb_ = blockIdx.y;           // 0..23
    const int qi = QI_T[yb_];
    const int hf = HF_T[yb_];             // 0/1 = split half, 2 = unsplit
    const int q0 = qi * 128;
    const int wrow = w * 16;
    const int jdiag = 2 * qi + (w >> 2);  // this wave's diagonal tile
    int j0, jend;
    if (hf == 2)      { j0 = 0;      jend = 2 * qi + 2; }
    else if (hf == 0) { j0 = 0;      jend = qi + 1; }
    else              { j0 = qi + 1; jend = 2 * qi + 2; }

    // Q fragments (pre-scaled + roped by qkv_gemm).  B-operand of S^T = K·Q^T.
    bf16x8 qf[4];
#pragma unroll
    for (int ks = 0; ks < 4; ++ks)
        qf[ks] = *(const bf16x8*)&q[(size_t)(b * TT + q0 + wrow + lm) * CC
                                    + h * HD + ks * 32 + q8 * 8];

    f32x4 o_acc[8];
#pragma unroll
    for (int nt = 0; nt < 8; ++nt) o_acc[nt] = {0.f, 0.f, 0.f, 0.f};
    float m_i = -1e30f;                   // row lm's running max (exp2 domain)
    float l_i = 0.f;                      // per-lane PARTIAL row sum

    // staging geometry: 1024 16B-chunks each for K and V over 512 threads
    int ktok[2], ke8[2], vd[2], vt8[2];
#pragma unroll
    for (int i = 0; i < 2; ++i) {
        int f = tid + i * 512;
        ktok[i] = f >> 4; ke8[i] = (f & 15) * 8;
        vd[i]   = f >> 3; vt8[i] = (f & 7) * 8;
    }
    const unsigned short* kbase = k + (size_t)(b * TT) * (HKK * HD) + g * HD;
    const unsigned short* vbase = vt + (size_t)((b * 4 + g) * HD) * TT;

    uint4 kreg[2], vreg[2];
#pragma unroll
    for (int i = 0; i < 2; ++i) {
        kreg[i] = *(const uint4*)&kbase[(size_t)(j0 * 64 + ktok[i]) * (HKK * HD) + ke8[i]];
        vreg[i] = *(const uint4*)&vbase[(size_t)vd[i] * TT + j0 * 64 + vt8[i]];
    }

    short* Pw = Ps + w * 16 * 68;
    const int mrow = (w & 3) * 16 + lm;   // diagonal-tile row offset

    for (int j = j0; j < jend; ++j) {
        __syncthreads();                 // prev iter's K/V LDS reads complete
#pragma unroll
        for (int i = 0; i < 2; ++i) {
            *(uint4*)&Ks[ktok[i] * 136 + ke8[i]] = kreg[i];
            *(uint4*)&Vs[vd[i] * 72 + vt8[i]]    = vreg[i];
        }
        __syncthreads();                 // tiles visible
        if (j + 1 < jend) {              // prefetch next tile (uniform branch)
#pragma unroll
            for (int i = 0; i < 2; ++i) {
                kreg[i] = *(const uint4*)&kbase[(size_t)((j + 1) * 64 + ktok[i]) * (HKK * HD) + ke8[i]];
                vreg[i] = *(const uint4*)&vbase[(size_t)vd[i] * TT + (j + 1) * 64 + vt8[i]];
            }
        }

        if (j <= jdiag) {
            // S^T = K·Q^T : C-layout col=lm -> qrow, row=q8*4+r -> token
            f32x4 sacc[4];
#pragma unroll
            for (int ct = 0; ct < 4; ++ct) {
                sacc[ct] = {0.f, 0.f, 0.f, 0.f};
#pragma unroll
                for (int ks = 0; ks < 4; ++ks) {
                    bf16x8 kf = *(const bf16x8*)&Ks[(ct * 16 + lm) * 136 + ks * 32 + q8 * 8];
                    sacc[ct] = __builtin_amdgcn_mfma_f32_16x16x32_bf16(kf, qf[ks], sacc[ct], 0, 0, 0);
                }
            }
            if (j == jdiag) {            // causal mask (only diagonal tile)
#pragma unroll
                for (int ct = 0; ct < 4; ++ct)
#pragma unroll
                    for (int r = 0; r < 4; ++r)
                        if (ct * 16 + q8 * 4 + r > mrow) sacc[ct][r] = -1e30f;
            }
            // row max: 15 in-lane + 2 cross-lane
            float tmax = fmaxf(
                fmaxf(fmaxf(fmaxf(sacc[0][0], sacc[0][1]), fmaxf(sacc[0][2], sacc[0][3])),
                      fmaxf(fmaxf(sacc[1][0], sacc[1][1]), fmaxf(sacc[1][2], sacc[1][3]))),
                fmaxf(fmaxf(fmaxf(sacc[2][0], sacc[2][1]), fmaxf(sacc[2][2], sacc[2][3])),
                      fmaxf(fmaxf(sacc[3][0], sacc[3][1]), fmaxf(sacc[3][2], sacc[3][3]))));
            tmax = fmaxf(tmax, __shfl_xor(tmax, 16));
            tmax = fmaxf(tmax, __shfl_xor(tmax, 32));
            float m_new = fmaxf(m_i, tmax);
            float alpha = exp2f(m_i - m_new);
            m_i = m_new;

            float ps = 0.f;
#pragma unroll
            for (int ct = 0; ct < 4; ++ct) {
                ushort4 pp;
                float p0 = exp2f(sacc[ct][0] - m_new);
                float p1 = exp2f(sacc[ct][1] - m_new);
                float p2 = exp2f(sacc[ct][2] - m_new);
                float p3 = exp2f(sacc[ct][3] - m_new);
                ps += (p0 + p1) + (p2 + p3);
                pp.x = f2bf(p0); pp.y = f2bf(p1); pp.z = f2bf(p2); pp.w = f2bf(p3);
                *(ushort4*)&Pw[lm * 68 + ct * 16 + q8 * 4] = pp;
            }
            l_i = l_i * alpha + ps;      // per-lane partial; alpha row-uniform

            float a0 = __shfl(alpha, q8 * 4 + 0);
            float a1 = __shfl(alpha, q8 * 4 + 1);
            float a2 = __shfl(alpha, q8 * 4 + 2);
            float a3 = __shfl(alpha, q8 * 4 + 3);
#pragma unroll
            for (int nt = 0; nt < 8; ++nt) {
                o_acc[nt][0] *= a0;
                o_acc[nt][1] *= a1;
                o_acc[nt][2] *= a2;
                o_acc[nt][3] *= a3;
            }

            // O += P·V
#pragma unroll
            for (int ks2 = 0; ks2 < 2; ++ks2) {
                bf16x8 pf = *(const bf16x8*)&Pw[lm * 68 + ks2 * 32 + q8 * 8];
#pragma unroll
                for (int nt = 0; nt < 8; ++nt) {
                    bf16x8 vf = *(const bf16x8*)&Vs[(nt * 16 + lm) * 72 + ks2 * 32 + q8 * 8];
                    o_acc[nt] = __builtin_amdgcn_mfma_f32_16x16x32_bf16(pf, vf, o_acc[nt], 0, 0, 0);
                }
            }
        }
    }

    // finalize l: sum partials over the 4 q8 groups, fetch per-o_acc-row
    float lf = l_i;
    lf += __shfl_xor(lf, 16);
    lf += __shfl_xor(lf, 32);
    float inv[4];
#pragma unroll
    for (int r = 0; r < 4; ++r) inv[r] = 1.f / __shfl(lf, q8 * 4 + r);

    if (hf == 2) {
        // Epilogue: stage O in LDS (128 rows x stride 136, over Ks+Vs space),
        // read back b128, store coalesced dwordx4.
        __syncthreads();                   // all waves done with Ks/Vs/Ps
        short* Es = SM;                    // 128*136 = 17408 shorts
#pragma unroll
        for (int nt = 0; nt < 8; ++nt)
#pragma unroll
            for (int r = 0; r < 4; ++r)
                Es[(wrow + q8 * 4 + r) * 136 + nt * 16 + lm] = (short)f2bf(o_acc[nt][r] * inv[r]);
        __syncthreads();
#pragma unroll
        for (int i = 0; i < 4; ++i) {
            int f = tid + i * 512;             // 0..2047
            int row = f >> 4, ch = f & 15;
            uint4 t = *(const uint4*)&Es[row * 136 + ch * 8];
            *(uint4*)&y[(size_t)(b * TT + q0 + row) * CC + h * HD + ch * 8] = t;
        }
    } else {
        // Split-chunk epilogue: normalized Ô (f32) + per-row s = l·2^m.
        const int pi = ((bh << 3) + (qi - 8)) * 2 + hf;
        if (lane < 16) sb[pi * 128 + wrow + lane] = lf * exp2f(m_i);
        float* pb = po + (size_t)pi * 16384;
#pragma unroll
        for (int nt = 0; nt < 8; ++nt)
#pragma unroll
            for (int r = 0; r < 4; ++r)
                pb[(wrow + q8 * 4 + r) * 128 + nt * 16 + lm] = o_acc[nt][r] * inv[r];
    }
}

// ---------------------------------------------------------------------------
// Merge the two KV-half partials of split tiles (qi 8..15):
//   O = (s0·Ô0 + s1·Ô1)/(s0+s1),  then bf16 -> y.
// ---------------------------------------------------------------------------
__global__ __launch_bounds__(256) void combine_kernel(
    const float* __restrict__ po, const float* __restrict__ sb,
    unsigned short* __restrict__ y)
{
    const int bh = blockIdx.x;             // 0..31
    const int b = bh >> 4, h = bh & 15;
    const int qi = 8 + blockIdx.y;         // 8..15
    const int p0 = ((bh << 3) + (qi - 8)) * 2;
    const int t = threadIdx.x;
    const int row = t >> 1, d0 = (t & 1) * 64;
    float s0 = sb[p0 * 128 + row];
    float s1 = sb[(p0 + 1) * 128 + row];
    float w0 = s0 / (s0 + s1);
    float w1 = 1.f - w0;
    const float* a = &po[(size_t)p0 * 16384 + row * 128 + d0];
    const float* c = &po[(size_t)(p0 + 1) * 16384 + row * 128 + d0];
    unsigned short* yr = &y[(size_t)(b * TT + qi * 128 + row) * CC + h * HD + d0];
#pragma unroll
    for (int i = 0; i < 64; i += 4) {
        float4 xa = *(const float4*)&a[i];
        float4 xc = *(const float4*)&c[i];
        ushort4 o;
        o.x = f2bf(w0 * xa.x + w1 * xc.x);
        o.y = f2bf(w0 * xa.y + w1 * xc.y);
        o.z = f2bf(w0 * xa.z + w1 * xc.z);
        o.w = f2bf(w0 * xa.w + w1 * xc.w);
        *(ushort4*)&yr[i] = o;
    }
}

// ---------------------------------------------------------------------------
extern "C" void kernel_launch(void* const* d_in, const int* in_sizes, int n_in,
                              void* d_out, int out_size, void* d_ws, size_t ws_size,
                              hipStream_t stream) {
    const float* x    = (const float*)d_in[0];
    const float* cosb = (const float*)d_in[1];
    const float* sinb = (const float*)d_in[2];
    const float* Wq   = (const float*)d_in[3];
    const float* bq   = (const float*)d_in[4];
    const float* Wk   = (const float*)d_in[5];
    const float* bk   = (const float*)d_in[6];
    const float* Wv   = (const float*)d_in[7];
    const float* bv   = (const float*)d_in[8];
    const float* Wo   = (const float*)d_in[9];
    float* out = (float*)d_out;

    // workspace (all bf16 as ushort):
    // xb[4096*2048] Wt[3072*2048] Wot[2048*2048] qb[4096*2048]
    // kb[4096*512] vb[4096*512] vtb[1024*2048] yb[4096*2048]  = 83.9 MB
    unsigned short* xb  = (unsigned short*)d_ws;
    unsigned short* Wt  = xb  + (size_t)MM * CC;
    unsigned short* Wot = Wt  + (size_t)3072 * 2048;
    unsigned short* qb  = Wot + (size_t)2048 * 2048;
    unsigned short* kb  = qb  + (size_t)MM * CC;
    unsigned short* vb  = kb  + (size_t)MM * (HKK * HD);
    unsigned short* vtb = vb  + (size_t)MM * (HKK * HD);
    unsigned short* ybf = vtb + (size_t)BB * HKK * HD * TT;

    // Scratch aliases for the split-KV flash path (no new workspace):
    //  - po: 512 partial tiles x 128x128 f32 = 33.55 MB == d_out size exactly
    //        (d_out is dead until out_gemm overwrites every element).
    //  - sb: 512x128 f32 row-scalars s = l*2^m, over dead xb (dead after qkv).
    float* po = (float*)d_out;
    float* sbuf = (float*)xb;

    cast_x_kernel<<<dim3((MM * CC) / 2048), 256, 0, stream>>>(x, xb);
    wtrans_kernel<<<dim3(32, 32, 4), 256, 0, stream>>>(Wq, Wk, Wv, Wo, Wt, Wot);
    qkv_gemm_mfma<<<dim3(3072 / 128, MM / 128), 256, 0, stream>>>(
        xb, Wt, bq, bk, bv, cosb, sinb, qb, kb, vb);
    vtrans_kernel<<<dim3(TT / 64, HD / 64, BB * HKK), 256, 0, stream>>>(vb, vtb);
    flash_mfma<<<dim3(BB * HH, 24), 512, 0, stream>>>(qb, kb, vtb, ybf, po, sbuf);
    combine_kernel<<<dim3(BB * HH, 8), 256, 0, stream>>>(po, sbuf, ybf);
    out_gemm_mfma<<<dim3(CC / 128, MM / 128), 256, 0, stream>>>(ybf, Wot, out);
}